// Round 9
// baseline (284.174 us; speedup 1.0000x reference)
//
#include <hip/hip_runtime.h>

#define N_NODES 100000
#define N_EDGES 800000
#define FIN 64
#define HID 128
#define NB1 391   // ceil(N_NODES/256)

typedef unsigned short ushort_t;
typedef __attribute__((ext_vector_type(8))) short short8;   // 8 bf16 = 4 VGPRs (MFMA A/B frag)
typedef __attribute__((ext_vector_type(16))) float fx16;    // 32x32 MFMA C/D frag
typedef __attribute__((ext_vector_type(4))) unsigned short us4;

__device__ inline ushort_t f2bf(float f) {   // RNE fp32 -> bf16
    unsigned u = __float_as_uint(f);
    u += 0x7fffu + ((u >> 16) & 1u);
    return (ushort_t)(u >> 16);
}
__device__ inline float bf2f(ushort_t h) { return __uint_as_float(((unsigned)h) << 16); }

// ---------------- fused prep: zero deg/flag + xcvt + wcvt + sentinel rows ----------------
// 6250 blocks x 256. Edge-index detect runs as its own (ordered-after) kernel.
__global__ void prep_kernel(const float* __restrict__ x, ushort_t* __restrict__ xb,
                            const float* __restrict__ W1rel, const float* __restrict__ W1root,
                            const float* __restrict__ W2rel, const float* __restrict__ W2root,
                            ushort_t* __restrict__ Wb1, ushort_t* __restrict__ Wb2,
                            int* __restrict__ deg, int* __restrict__ flag,
                            ushort_t* __restrict__ h1b) {
    int i = blockIdx.x * 256 + threadIdx.x;
    if (i < N_NODES * FIN / 4) {                 // x -> bf16
        float4 v = ((const float4*)x)[i];
        us4 o = {f2bf(v.x), f2bf(v.y), f2bf(v.z), f2bf(v.w)};
        ((us4*)xb)[i] = o;
    }
    if (i < HID * HID) {                         // Wb1 = [W1rel | W1root]
        int n = i >> 7, k = i & 127;
        float v = (k < FIN) ? W1rel[n * FIN + k] : W1root[n * FIN + (k - FIN)];
        Wb1[i] = f2bf(v);
    }
    if (i < HID * 2 * HID) {                     // Wb2 = [W2rel | W2root]
        int n = i >> 8, k = i & 255;
        float v = (k < HID) ? W2rel[n * HID + k] : W2root[n * HID + (k - HID)];
        Wb2[i] = f2bf(v);
    }
    if (i < N_NODES) deg[i] = 0;
    if (i == 0) *flag = 0;
    // sentinel rows (index N_NODES) = zeros: tail gather slots read these for free
    uint4 z = {0u, 0u, 0u, 0u};
    if (i < 8)  ((uint4*)(xb + (size_t)N_NODES * FIN))[i] = z;
    else if (i < 24) ((uint4*)(h1b + (size_t)N_NODES * HID))[i - 8] = z;
}

// int32 vs int64 edge_index layout probe (int64 little-endian => odd words all 0)
__global__ void detect_kernel(const int* __restrict__ w, int* __restrict__ flag) {
    int i = blockIdx.x * 256 + threadIdx.x;
    if (i < 8192) {
        if (w[2 * i + 1] != 0) atomicOr(flag, 1);
    }
}

// ---------------- CSR build ----------------
__global__ void hist_kernel(const int* __restrict__ w, const int* __restrict__ flag,
                            int* __restrict__ deg, int* __restrict__ rank) {
    int e = blockIdx.x * 256 + threadIdx.x;
    if (e >= N_EDGES) return;
    int is32 = *flag;
    int d = is32 ? w[N_EDGES + e] : w[2 * (N_EDGES + e)];
    rank[e] = atomicAdd(&deg[d], 1);
}

__global__ void scan1_kernel(const int* __restrict__ deg, int* __restrict__ off,
                             int* __restrict__ bsums) {
    __shared__ int s[256];
    int t = threadIdx.x;
    int i = blockIdx.x * 256 + t;
    int v = (i < N_NODES) ? deg[i] : 0;
    s[t] = v;
    __syncthreads();
    for (int d = 1; d < 256; d <<= 1) {
        int w = (t >= d) ? s[t - d] : 0;
        __syncthreads();
        s[t] += w;
        __syncthreads();
    }
    if (i < N_NODES) off[i] = s[t] - v;
    if (t == 255) bsums[blockIdx.x] = s[255];
}

__global__ void scan2_kernel(int* __restrict__ bsums) {
    __shared__ int s[512];
    int t = threadIdx.x;
    int v = (t < NB1) ? bsums[t] : 0;
    s[t] = v;
    __syncthreads();
    for (int d = 1; d < 512; d <<= 1) {
        int w = (t >= d) ? s[t - d] : 0;
        __syncthreads();
        s[t] += w;
        __syncthreads();
    }
    if (t < NB1) bsums[t] = s[t] - v;
}

__global__ void scan3_kernel(int* __restrict__ off, const int* __restrict__ bsums) {
    int i = blockIdx.x * 256 + threadIdx.x;
    if (i < N_NODES) off[i] = off[i] + bsums[blockIdx.x];
    if (i == 0) off[N_NODES] = N_EDGES;
}

__global__ void scatter_kernel(const int* __restrict__ w, const int* __restrict__ flag,
                               const int* __restrict__ off, const int* __restrict__ rank,
                               int* __restrict__ srcs) {
    int e = blockIdx.x * 256 + threadIdx.x;
    if (e >= N_EDGES) return;
    int is32 = *flag;
    int s = is32 ? w[e] : w[2 * e];
    int d = is32 ? w[N_EDGES + e] : w[2 * (N_EDGES + e)];
    srcs[off[d] + rank[e]] = s;
}

// ------- aggregation: wave per node, slot-parallel vectorized gather -------
// Tail slots clamp the source index to the zero sentinel row (N_NODES) —
// no per-word cndmask sanitization; sentinel lines are L2-hot (free-ish).
__global__ void agg1_kernel(const ushort_t* __restrict__ xb, const int* __restrict__ off,
                            const int* __restrict__ srcs, ushort_t* __restrict__ aggb) {
    int wid = (blockIdx.x * 256 + threadIdx.x) >> 6; // node
    int lane = threadIdx.x & 63;
    if (wid >= N_NODES) return;
    int b = __builtin_amdgcn_readfirstlane(off[wid]);
    int e = __builtin_amdgcn_readfirstlane(off[wid + 1]);
    int g = lane >> 3;   // edge slot 0..7
    int c = lane & 7;    // 16B chunk of the 128B row
    float acc[8];
#pragma unroll
    for (int j = 0; j < 8; j++) acc[j] = 0.f;
    const uint4* rows = (const uint4*)xb;    // 8 chunks per row
    for (int p = b; p < e; p += 8) {
        int i0 = p + g;
        bool q0 = i0 < e;
        int s0 = srcs[q0 ? i0 : 0];
        s0 = q0 ? s0 : N_NODES;              // sentinel: zero row
        uint4 A = rows[(size_t)s0 * 8 + c];
        acc[0] += __uint_as_float(A.x << 16);
        acc[1] += __uint_as_float(A.x & 0xffff0000u);
        acc[2] += __uint_as_float(A.y << 16);
        acc[3] += __uint_as_float(A.y & 0xffff0000u);
        acc[4] += __uint_as_float(A.z << 16);
        acc[5] += __uint_as_float(A.z & 0xffff0000u);
        acc[6] += __uint_as_float(A.w << 16);
        acc[7] += __uint_as_float(A.w & 0xffff0000u);
    }
#pragma unroll
    for (int j = 0; j < 8; j++) {
        acc[j] += __shfl_xor(acc[j], 8);
        acc[j] += __shfl_xor(acc[j], 16);
        acc[j] += __shfl_xor(acc[j], 32);
    }
    if (lane < 8) {
        unsigned w0 = (unsigned)f2bf(acc[0]) | ((unsigned)f2bf(acc[1]) << 16);
        unsigned w1 = (unsigned)f2bf(acc[2]) | ((unsigned)f2bf(acc[3]) << 16);
        unsigned w2 = (unsigned)f2bf(acc[4]) | ((unsigned)f2bf(acc[5]) << 16);
        unsigned w3 = (unsigned)f2bf(acc[6]) | ((unsigned)f2bf(acc[7]) << 16);
        uint4 o = {w0, w1, w2, w3};
        ((uint4*)(aggb + (size_t)wid * FIN))[lane] = o;
    }
}

__global__ void agg2_kernel(const ushort_t* __restrict__ h1b, const int* __restrict__ off,
                            const int* __restrict__ srcs, ushort_t* __restrict__ aggb) {
    int wid = (blockIdx.x * 256 + threadIdx.x) >> 6; // node
    int lane = threadIdx.x & 63;
    if (wid >= N_NODES) return;
    int b = __builtin_amdgcn_readfirstlane(off[wid]);
    int e = __builtin_amdgcn_readfirstlane(off[wid + 1]);
    int g = lane >> 4;   // edge slot 0..3
    int c = lane & 15;   // 16B chunk of the 256B row
    float acc[8];
#pragma unroll
    for (int j = 0; j < 8; j++) acc[j] = 0.f;
    const uint4* rows = (const uint4*)h1b;   // 16 chunks per row
    for (int p = b; p < e; p += 8) {
        int i0 = p + g, i1 = p + 4 + g;
        bool q0 = i0 < e, q1 = i1 < e;
        int s0 = srcs[q0 ? i0 : 0];
        int s1 = srcs[q1 ? i1 : 0];
        s0 = q0 ? s0 : N_NODES;              // sentinel: zero row
        s1 = q1 ? s1 : N_NODES;
        uint4 A = rows[(size_t)s0 * 16 + c];
        uint4 B = rows[(size_t)s1 * 16 + c];
        acc[0] += __uint_as_float(A.x << 16) + __uint_as_float(B.x << 16);
        acc[1] += __uint_as_float(A.x & 0xffff0000u) + __uint_as_float(B.x & 0xffff0000u);
        acc[2] += __uint_as_float(A.y << 16) + __uint_as_float(B.y << 16);
        acc[3] += __uint_as_float(A.y & 0xffff0000u) + __uint_as_float(B.y & 0xffff0000u);
        acc[4] += __uint_as_float(A.z << 16) + __uint_as_float(B.z << 16);
        acc[5] += __uint_as_float(A.z & 0xffff0000u) + __uint_as_float(B.z & 0xffff0000u);
        acc[6] += __uint_as_float(A.w << 16) + __uint_as_float(B.w << 16);
        acc[7] += __uint_as_float(A.w & 0xffff0000u) + __uint_as_float(B.w & 0xffff0000u);
    }
#pragma unroll
    for (int j = 0; j < 8; j++) {
        acc[j] += __shfl_xor(acc[j], 16);
        acc[j] += __shfl_xor(acc[j], 32);
    }
    if (lane < 16) {
        unsigned w0 = (unsigned)f2bf(acc[0]) | ((unsigned)f2bf(acc[1]) << 16);
        unsigned w1 = (unsigned)f2bf(acc[2]) | ((unsigned)f2bf(acc[3]) << 16);
        unsigned w2 = (unsigned)f2bf(acc[4]) | ((unsigned)f2bf(acc[5]) << 16);
        unsigned w3 = (unsigned)f2bf(acc[6]) | ((unsigned)f2bf(acc[7]) << 16);
        uint4 o = {w0, w1, w2, w3};
        ((uint4*)(aggb + (size_t)wid * HID))[lane] = o;
    }
}

// ------- MFMA GEMM layer 1: h1 = elu([agg1,x] @ Wb1^T + b1) -------
// 256 nodes/block (2 sequential M-tiles per wave): halves weight staging + block count.
__global__ __launch_bounds__(256) void g1_kernel(
    const ushort_t* __restrict__ aggb, const ushort_t* __restrict__ xb,
    const ushort_t* __restrict__ Wb1, const float* __restrict__ b1,
    ushort_t* __restrict__ h1b) {
    __shared__ short8 wl8[2048];                 // 32 KB
    ushort_t* wl = (ushort_t*)wl8;
#pragma unroll
    for (int it = 0; it < 8; it++) {
        int q = it * 256 + threadIdx.x;
        int n = q >> 4, c = q & 15;
        short8 v = ((const short8*)Wb1)[q];
        *(short8*)(wl + n * HID + ((c ^ (n & 7)) << 3)) = v;
    }
    __syncthreads();

    int wave = threadIdx.x >> 6;
    int lane = threadIdx.x & 63;
    int half = lane >> 5, col = lane & 31;

#pragma unroll
    for (int mt = 0; mt < 2; mt++) {
        int nb = blockIdx.x * 256 + mt * 128 + wave * 32;
        if (nb >= N_NODES) continue;             // no barriers below: safe
        int nA = nb + col;
        if (nA >= N_NODES) nA = N_NODES - 1;

        short8 areg[8];
#pragma unroll
        for (int s = 0; s < 4; s++)
            areg[s] = *(const short8*)(aggb + (size_t)nA * FIN + s * 16 + half * 8);
#pragma unroll
        for (int s = 4; s < 8; s++)
            areg[s] = *(const short8*)(xb + (size_t)nA * FIN + (s - 4) * 16 + half * 8);

        fx16 acc[4];
#pragma unroll
        for (int jt = 0; jt < 4; jt++)
#pragma unroll
            for (int r = 0; r < 16; r++) acc[jt][r] = 0.f;

#pragma unroll
        for (int s = 0; s < 8; s++) {
            int c = 2 * s + half;
#pragma unroll
            for (int jt = 0; jt < 4; jt++) {
                int n = jt * 32 + col;
                short8 bq = *(const short8*)(wl + n * HID + ((c ^ (n & 7)) << 3));
                acc[jt] = __builtin_amdgcn_mfma_f32_32x32x16_bf16(areg[s], bq, acc[jt], 0, 0, 0);
            }
        }
#pragma unroll
        for (int jt = 0; jt < 4; jt++) {
            int j = jt * 32 + col;
            float bias = b1[j];
#pragma unroll
            for (int r = 0; r < 16; r++) {
                int node = nb + (r & 3) + 8 * (r >> 2) + 4 * half;
                if (node < N_NODES) {
                    float v = acc[jt][r] + bias;
                    v = v > 0.f ? v : __expf(v) - 1.f;
                    h1b[(size_t)node * HID + j] = f2bf(v);
                }
            }
        }
    }
}

// ------- MFMA GEMM layer 2 + MFMA MLP head (unchanged from R8) -------
__global__ __launch_bounds__(256) void g2h_kernel(
    const ushort_t* __restrict__ agg2b, const ushort_t* __restrict__ h1b,
    const ushort_t* __restrict__ Wb2, const float* __restrict__ b2,
    const float* __restrict__ Wfc1, const float* __restrict__ bfc1,
    const float* __restrict__ Wfc2, const float* __restrict__ bfc2,
    float* __restrict__ out) {
    __shared__ ushort_t smem[21504];             // 43008 B
    ushort_t* wl = smem;                         // 32 KB Wb2 K-half staging / t2 tile
    ushort_t* wf = smem + 17408;                 // 8 KB Wfc1 padded 32x128

#pragma unroll
    for (int it = 0; it < 16; it++) {
        int idx = it * 256 + threadIdx.x;        // 0..4095
        int m = idx >> 7, k = idx & 127;
        float v = (m < 20) ? Wfc1[m * HID + k] : 0.f;
        wf[m * 128 + (((k >> 3) ^ (m & 7)) << 3) + (k & 7)] = f2bf(v);
    }
#pragma unroll
    for (int it = 0; it < 8; it++) {
        int q = it * 256 + threadIdx.x;          // 0..2047
        int n = q >> 4, c = q & 15;
        short8 v = *(const short8*)(Wb2 + (size_t)n * 256 + c * 8);
        *(short8*)(wl + n * 128 + ((c ^ (n & 7)) << 3)) = v;
    }

    int wave = threadIdx.x >> 6;
    int lane = threadIdx.x & 63;
    int half = lane >> 5, col = lane & 31;
    int nb = blockIdx.x * 128 + wave * 32;       // tail waves keep running (barriers!)
    int nA = nb + col;
    if (nA >= N_NODES) nA = N_NODES - 1;

    short8 areg[16];
#pragma unroll
    for (int s = 0; s < 8; s++)
        areg[s] = *(const short8*)(agg2b + (size_t)nA * HID + s * 16 + half * 8);
#pragma unroll
    for (int s = 8; s < 16; s++)
        areg[s] = *(const short8*)(h1b + (size_t)nA * HID + (s - 8) * 16 + half * 8);

    fx16 acc[4];
#pragma unroll
    for (int jt = 0; jt < 4; jt++)
#pragma unroll
        for (int r = 0; r < 16; r++) acc[jt][r] = 0.f;

    __syncthreads();
#pragma unroll
    for (int s = 0; s < 8; s++) {                // K 0..127 (agg2 part)
        int c = 2 * s + half;
#pragma unroll
        for (int jt = 0; jt < 4; jt++) {
            int n = jt * 32 + col;
            short8 bq = *(const short8*)(wl + n * 128 + ((c ^ (n & 7)) << 3));
            acc[jt] = __builtin_amdgcn_mfma_f32_32x32x16_bf16(areg[s], bq, acc[jt], 0, 0, 0);
        }
    }
    __syncthreads();
#pragma unroll
    for (int it = 0; it < 8; it++) {             // stage K-half 1
        int q = it * 256 + threadIdx.x;
        int n = q >> 4, c = q & 15;
        short8 v = *(const short8*)(Wb2 + (size_t)n * 256 + 128 + c * 8);
        *(short8*)(wl + n * 128 + ((c ^ (n & 7)) << 3)) = v;
    }
    __syncthreads();
#pragma unroll
    for (int s = 8; s < 16; s++) {               // K 128..255 (h1 part)
        int c = 2 * (s - 8) + half;
#pragma unroll
        for (int jt = 0; jt < 4; jt++) {
            int n = jt * 32 + col;
            short8 bq = *(const short8*)(wl + n * 128 + ((c ^ (n & 7)) << 3));
            acc[jt] = __builtin_amdgcn_mfma_f32_32x32x16_bf16(areg[s], bq, acc[jt], 0, 0, 0);
        }
    }
    __syncthreads();   // weights dead; reuse as t2 tile

    ushort_t* tl = smem;                         // [node][feature], stride 136
#pragma unroll
    for (int jt = 0; jt < 4; jt++) {
        int j = jt * 32 + col;
        float bias = b2[j];
#pragma unroll
        for (int r = 0; r < 16; r++) {
            int nl = wave * 32 + (r & 3) + 8 * (r >> 2) + 4 * half;
            tl[nl * 136 + j] = f2bf(acc[jt][r] + bias);
        }
    }
    __syncthreads();

    short8 af[8];
#pragma unroll
    for (int s = 0; s < 8; s++)
        af[s] = *(const short8*)(tl + (wave * 32 + col) * 136 + s * 16 + half * 8);
    fx16 fa;
#pragma unroll
    for (int r = 0; r < 16; r++) fa[r] = 0.f;
#pragma unroll
    for (int s = 0; s < 8; s++) {
        int c = 2 * s + half;
        short8 bw = *(const short8*)(wf + col * 128 + ((c ^ (col & 7)) << 3));
        fa = __builtin_amdgcn_mfma_f32_32x32x16_bf16(af[s], bw, fa, 0, 0, 0);
    }
    float biasv = (col < 20) ? bfc1[col] : 0.f;
    float w2v = (col < 20) ? Wfc2[col] : 0.f;
    float bz = bfc2[0];
    float red[16];
#pragma unroll
    for (int r = 0; r < 16; r++) {
        float v = fa[r] + biasv;
        v = (v > 0.f ? v : 0.f) * w2v;
        v += __shfl_xor(v, 1);
        v += __shfl_xor(v, 2);
        v += __shfl_xor(v, 4);
        v += __shfl_xor(v, 8);
        v += __shfl_xor(v, 16);
        red[r] = v;
    }
    if (col == 0) {
#pragma unroll
        for (int r = 0; r < 16; r++) {
            int nl = wave * 32 + (r & 3) + 8 * (r >> 2) + 4 * half;
            int ng = blockIdx.x * 128 + nl;
            if (ng < N_NODES) out[ng] = red[r] + bz;
        }
    }
}

// ---------------- launch ----------------
extern "C" void kernel_launch(void* const* d_in, const int* in_sizes, int n_in,
                              void* d_out, int out_size, void* d_ws, size_t ws_size,
                              hipStream_t stream) {
    const float* x = (const float*)d_in[0];
    const int* ei = (const int*)d_in[1];
    const float* W1rel = (const float*)d_in[2];
    const float* b1 = (const float*)d_in[3];
    const float* W1root = (const float*)d_in[4];
    const float* W2rel = (const float*)d_in[5];
    const float* b2 = (const float*)d_in[6];
    const float* W2root = (const float*)d_in[7];
    const float* Wfc1 = (const float*)d_in[8];
    const float* bfc1 = (const float*)d_in[9];
    const float* Wfc2 = (const float*)d_in[10];
    const float* bfc2 = (const float*)d_in[11];
    float* out = (float*)d_out;

    char* ws = (char*)d_ws;
    size_t o = 0;
    int* deg = (int*)(ws + o);       o += (size_t)N_NODES * 4;
    int* off = (int*)(ws + o);       o += (size_t)(N_NODES + 1) * 4 + 12;
    int* bsums = (int*)(ws + o);     o += 4096;
    int* flag = (int*)(ws + o);      o += 16;
    int* rank = (int*)(ws + o);      o += (size_t)N_EDGES * 4;              // 3.2 MB
    int* srcs = (int*)(ws + o);      o += (size_t)N_EDGES * 4;              // 3.2 MB
    ushort_t* xb = (ushort_t*)(ws + o);    o += (size_t)(N_NODES + 1) * FIN * 2;  // +sentinel
    ushort_t* agg1b = (ushort_t*)(ws + o); o += (size_t)N_NODES * FIN * 2;
    ushort_t* h1b = (ushort_t*)(ws + o);   o += (size_t)(N_NODES + 1) * HID * 2;  // +sentinel
    ushort_t* agg2b = (ushort_t*)(ws + o); o += (size_t)N_NODES * HID * 2;
    ushort_t* Wb1 = (ushort_t*)(ws + o);   o += (size_t)HID * HID * 2;
    ushort_t* Wb2 = (ushort_t*)(ws + o);   o += (size_t)HID * 2 * HID * 2;

    const int GW2 = (N_NODES + 127) / 128; // 782 blocks (g2h)
    const int GW1 = (N_NODES + 255) / 256; // 391 blocks (g1, 2 M-tiles/wave)

    prep_kernel<<<(N_NODES * FIN / 4 + 255) / 256, 256, 0, stream>>>(
        x, xb, W1rel, W1root, W2rel, W2root, Wb1, Wb2, deg, flag, h1b);
    detect_kernel<<<32, 256, 0, stream>>>(ei, flag);
    hist_kernel<<<(N_EDGES + 255) / 256, 256, 0, stream>>>(ei, flag, deg, rank);
    scan1_kernel<<<NB1, 256, 0, stream>>>(deg, off, bsums);
    scan2_kernel<<<1, 512, 0, stream>>>(bsums);
    scan3_kernel<<<NB1, 256, 0, stream>>>(off, bsums);
    scatter_kernel<<<(N_EDGES + 255) / 256, 256, 0, stream>>>(ei, flag, off, rank, srcs);
    agg1_kernel<<<N_NODES / 4, 256, 0, stream>>>(xb, off, srcs, agg1b);
    g1_kernel<<<GW1, 256, 0, stream>>>(agg1b, xb, Wb1, b1, h1b);
    agg2_kernel<<<N_NODES / 4, 256, 0, stream>>>(h1b, off, srcs, agg2b);
    g2h_kernel<<<GW2, 256, 0, stream>>>(agg2b, h1b, Wb2, b2, Wfc1, bfc1, Wfc2, bfc2, out);
}

// Round 10
// 283.132 us; speedup vs baseline: 1.0037x; 1.0037x over previous
//
#include <hip/hip_runtime.h>

#define N_NODES 100000
#define N_EDGES 800000
#define FIN 64
#define HID 128
#define NB1 391   // ceil(N_NODES/256)

typedef unsigned short ushort_t;
typedef __attribute__((ext_vector_type(8))) short short8;   // 8 bf16 = 4 VGPRs (MFMA A/B frag)
typedef __attribute__((ext_vector_type(16))) float fx16;    // 32x32 MFMA C/D frag
typedef __attribute__((ext_vector_type(4))) unsigned short us4;

__device__ inline ushort_t f2bf(float f) {   // RNE fp32 -> bf16
    unsigned u = __float_as_uint(f);
    u += 0x7fffu + ((u >> 16) & 1u);
    return (ushort_t)(u >> 16);
}
__device__ inline float bf2f(ushort_t h) { return __uint_as_float(((unsigned)h) << 16); }

// ---------------- fused prep: zero deg/flag + xcvt + wcvt + sentinel rows ----------------
__global__ void prep_kernel(const float* __restrict__ x, ushort_t* __restrict__ xb,
                            const float* __restrict__ W1rel, const float* __restrict__ W1root,
                            const float* __restrict__ W2rel, const float* __restrict__ W2root,
                            ushort_t* __restrict__ Wb1, ushort_t* __restrict__ Wb2,
                            int* __restrict__ deg, int* __restrict__ flag,
                            ushort_t* __restrict__ h1b) {
    int i = blockIdx.x * 256 + threadIdx.x;
    if (i < N_NODES * FIN / 4) {                 // x -> bf16
        float4 v = ((const float4*)x)[i];
        us4 o = {f2bf(v.x), f2bf(v.y), f2bf(v.z), f2bf(v.w)};
        ((us4*)xb)[i] = o;
    }
    if (i < HID * HID) {                         // Wb1 = [W1rel | W1root]
        int n = i >> 7, k = i & 127;
        float v = (k < FIN) ? W1rel[n * FIN + k] : W1root[n * FIN + (k - FIN)];
        Wb1[i] = f2bf(v);
    }
    if (i < HID * 2 * HID) {                     // Wb2 = [W2rel | W2root]
        int n = i >> 8, k = i & 255;
        float v = (k < HID) ? W2rel[n * HID + k] : W2root[n * HID + (k - HID)];
        Wb2[i] = f2bf(v);
    }
    if (i < N_NODES) deg[i] = 0;
    if (i == 0) *flag = 0;
    // sentinel rows (index N_NODES) = zeros: tail gather slots read these for free
    uint4 z = {0u, 0u, 0u, 0u};
    if (i < 8)  ((uint4*)(xb + (size_t)N_NODES * FIN))[i] = z;
    else if (i < 24) ((uint4*)(h1b + (size_t)N_NODES * HID))[i - 8] = z;
}

// int32 vs int64 edge_index layout probe (int64 little-endian => odd words all 0)
__global__ void detect_kernel(const int* __restrict__ w, int* __restrict__ flag) {
    int i = blockIdx.x * 256 + threadIdx.x;
    if (i < 8192) {
        if (w[2 * i + 1] != 0) atomicOr(flag, 1);
    }
}

// ---------------- CSR build ----------------
__global__ void hist_kernel(const int* __restrict__ w, const int* __restrict__ flag,
                            int* __restrict__ deg, int* __restrict__ rank) {
    int e = blockIdx.x * 256 + threadIdx.x;
    if (e >= N_EDGES) return;
    int is32 = *flag;
    int d = is32 ? w[N_EDGES + e] : w[2 * (N_EDGES + e)];
    rank[e] = atomicAdd(&deg[d], 1);
}

__global__ void scan1_kernel(const int* __restrict__ deg, int* __restrict__ off,
                             int* __restrict__ bsums) {
    __shared__ int s[256];
    int t = threadIdx.x;
    int i = blockIdx.x * 256 + t;
    int v = (i < N_NODES) ? deg[i] : 0;
    s[t] = v;
    __syncthreads();
    for (int d = 1; d < 256; d <<= 1) {
        int w = (t >= d) ? s[t - d] : 0;
        __syncthreads();
        s[t] += w;
        __syncthreads();
    }
    if (i < N_NODES) off[i] = s[t] - v;
    if (t == 255) bsums[blockIdx.x] = s[255];
}

__global__ void scan2_kernel(int* __restrict__ bsums) {
    __shared__ int s[512];
    int t = threadIdx.x;
    int v = (t < NB1) ? bsums[t] : 0;
    s[t] = v;
    __syncthreads();
    for (int d = 1; d < 512; d <<= 1) {
        int w = (t >= d) ? s[t - d] : 0;
        __syncthreads();
        s[t] += w;
        __syncthreads();
    }
    if (t < NB1) bsums[t] = s[t] - v;
}

__global__ void scan3_kernel(int* __restrict__ off, const int* __restrict__ bsums) {
    int i = blockIdx.x * 256 + threadIdx.x;
    if (i < N_NODES) off[i] = off[i] + bsums[blockIdx.x];
    if (i == 0) off[N_NODES] = N_EDGES;
}

__global__ void scatter_kernel(const int* __restrict__ w, const int* __restrict__ flag,
                               const int* __restrict__ off, const int* __restrict__ rank,
                               int* __restrict__ srcs) {
    int e = blockIdx.x * 256 + threadIdx.x;
    if (e >= N_EDGES) return;
    int is32 = *flag;
    int s = is32 ? w[e] : w[2 * e];
    int d = is32 ? w[N_EDGES + e] : w[2 * (N_EDGES + e)];
    srcs[off[d] + rank[e]] = s;
}

// ------- aggregation: wave per node, slot-parallel gather, 16 edges in flight -------
// In-flight model: 44 us at 8 edges/wave-iter == 11 B/cyc/CU request occupancy;
// 16 edges/iter doubles outstanding lines to push toward the HBM random-gather cap.
__global__ void agg1_kernel(const ushort_t* __restrict__ xb, const int* __restrict__ off,
                            const int* __restrict__ srcs, ushort_t* __restrict__ aggb) {
    int wid = (blockIdx.x * 256 + threadIdx.x) >> 6; // node
    int lane = threadIdx.x & 63;
    if (wid >= N_NODES) return;
    int b = __builtin_amdgcn_readfirstlane(off[wid]);
    int e = __builtin_amdgcn_readfirstlane(off[wid + 1]);
    int g = lane >> 3;   // edge slot 0..7
    int c = lane & 7;    // 16B chunk of the 128B row
    float acc[8];
#pragma unroll
    for (int j = 0; j < 8; j++) acc[j] = 0.f;
    const uint4* rows = (const uint4*)xb;    // 8 chunks per row
    for (int p = b; p < e; p += 16) {
        int i0 = p + g, i1 = p + 8 + g;
        bool q0 = i0 < e, q1 = i1 < e;
        int s0 = srcs[q0 ? i0 : 0]; s0 = q0 ? s0 : N_NODES;  // sentinel zero row
        int s1 = srcs[q1 ? i1 : 0]; s1 = q1 ? s1 : N_NODES;
        uint4 A = rows[(size_t)s0 * 8 + c];
        uint4 B = rows[(size_t)s1 * 8 + c];
        acc[0] += __uint_as_float(A.x << 16) + __uint_as_float(B.x << 16);
        acc[1] += __uint_as_float(A.x & 0xffff0000u) + __uint_as_float(B.x & 0xffff0000u);
        acc[2] += __uint_as_float(A.y << 16) + __uint_as_float(B.y << 16);
        acc[3] += __uint_as_float(A.y & 0xffff0000u) + __uint_as_float(B.y & 0xffff0000u);
        acc[4] += __uint_as_float(A.z << 16) + __uint_as_float(B.z << 16);
        acc[5] += __uint_as_float(A.z & 0xffff0000u) + __uint_as_float(B.z & 0xffff0000u);
        acc[6] += __uint_as_float(A.w << 16) + __uint_as_float(B.w << 16);
        acc[7] += __uint_as_float(A.w & 0xffff0000u) + __uint_as_float(B.w & 0xffff0000u);
    }
#pragma unroll
    for (int j = 0; j < 8; j++) {
        acc[j] += __shfl_xor(acc[j], 8);
        acc[j] += __shfl_xor(acc[j], 16);
        acc[j] += __shfl_xor(acc[j], 32);
    }
    if (lane < 8) {
        unsigned w0 = (unsigned)f2bf(acc[0]) | ((unsigned)f2bf(acc[1]) << 16);
        unsigned w1 = (unsigned)f2bf(acc[2]) | ((unsigned)f2bf(acc[3]) << 16);
        unsigned w2 = (unsigned)f2bf(acc[4]) | ((unsigned)f2bf(acc[5]) << 16);
        unsigned w3 = (unsigned)f2bf(acc[6]) | ((unsigned)f2bf(acc[7]) << 16);
        uint4 o = {w0, w1, w2, w3};
        ((uint4*)(aggb + (size_t)wid * FIN))[lane] = o;
    }
}

__global__ void agg2_kernel(const ushort_t* __restrict__ h1b, const int* __restrict__ off,
                            const int* __restrict__ srcs, ushort_t* __restrict__ aggb) {
    int wid = (blockIdx.x * 256 + threadIdx.x) >> 6; // node
    int lane = threadIdx.x & 63;
    if (wid >= N_NODES) return;
    int b = __builtin_amdgcn_readfirstlane(off[wid]);
    int e = __builtin_amdgcn_readfirstlane(off[wid + 1]);
    int g = lane >> 4;   // edge slot 0..3
    int c = lane & 15;   // 16B chunk of the 256B row
    float acc[8];
#pragma unroll
    for (int j = 0; j < 8; j++) acc[j] = 0.f;
    const uint4* rows = (const uint4*)h1b;   // 16 chunks per row
    for (int p = b; p < e; p += 16) {
        int i0 = p + g, i1 = p + 4 + g, i2 = p + 8 + g, i3 = p + 12 + g;
        bool q0 = i0 < e, q1 = i1 < e, q2 = i2 < e, q3 = i3 < e;
        int s0 = srcs[q0 ? i0 : 0]; s0 = q0 ? s0 : N_NODES;  // sentinel zero row
        int s1 = srcs[q1 ? i1 : 0]; s1 = q1 ? s1 : N_NODES;
        int s2 = srcs[q2 ? i2 : 0]; s2 = q2 ? s2 : N_NODES;
        int s3 = srcs[q3 ? i3 : 0]; s3 = q3 ? s3 : N_NODES;
        uint4 A = rows[(size_t)s0 * 16 + c];
        uint4 B = rows[(size_t)s1 * 16 + c];
        uint4 C = rows[(size_t)s2 * 16 + c];
        uint4 D = rows[(size_t)s3 * 16 + c];
        acc[0] += (__uint_as_float(A.x << 16) + __uint_as_float(B.x << 16)) +
                  (__uint_as_float(C.x << 16) + __uint_as_float(D.x << 16));
        acc[1] += (__uint_as_float(A.x & 0xffff0000u) + __uint_as_float(B.x & 0xffff0000u)) +
                  (__uint_as_float(C.x & 0xffff0000u) + __uint_as_float(D.x & 0xffff0000u));
        acc[2] += (__uint_as_float(A.y << 16) + __uint_as_float(B.y << 16)) +
                  (__uint_as_float(C.y << 16) + __uint_as_float(D.y << 16));
        acc[3] += (__uint_as_float(A.y & 0xffff0000u) + __uint_as_float(B.y & 0xffff0000u)) +
                  (__uint_as_float(C.y & 0xffff0000u) + __uint_as_float(D.y & 0xffff0000u));
        acc[4] += (__uint_as_float(A.z << 16) + __uint_as_float(B.z << 16)) +
                  (__uint_as_float(C.z << 16) + __uint_as_float(D.z << 16));
        acc[5] += (__uint_as_float(A.z & 0xffff0000u) + __uint_as_float(B.z & 0xffff0000u)) +
                  (__uint_as_float(C.z & 0xffff0000u) + __uint_as_float(D.z & 0xffff0000u));
        acc[6] += (__uint_as_float(A.w << 16) + __uint_as_float(B.w << 16)) +
                  (__uint_as_float(C.w << 16) + __uint_as_float(D.w << 16));
        acc[7] += (__uint_as_float(A.w & 0xffff0000u) + __uint_as_float(B.w & 0xffff0000u)) +
                  (__uint_as_float(C.w & 0xffff0000u) + __uint_as_float(D.w & 0xffff0000u));
    }
#pragma unroll
    for (int j = 0; j < 8; j++) {
        acc[j] += __shfl_xor(acc[j], 16);
        acc[j] += __shfl_xor(acc[j], 32);
    }
    if (lane < 16) {
        unsigned w0 = (unsigned)f2bf(acc[0]) | ((unsigned)f2bf(acc[1]) << 16);
        unsigned w1 = (unsigned)f2bf(acc[2]) | ((unsigned)f2bf(acc[3]) << 16);
        unsigned w2 = (unsigned)f2bf(acc[4]) | ((unsigned)f2bf(acc[5]) << 16);
        unsigned w3 = (unsigned)f2bf(acc[6]) | ((unsigned)f2bf(acc[7]) << 16);
        uint4 o = {w0, w1, w2, w3};
        ((uint4*)(aggb + (size_t)wid * HID))[lane] = o;
    }
}

// ------- MFMA GEMM layer 1: h1 = elu([agg1,x] @ Wb1^T + b1) -------
// 256 nodes/block (2 sequential M-tiles per wave).
__global__ __launch_bounds__(256) void g1_kernel(
    const ushort_t* __restrict__ aggb, const ushort_t* __restrict__ xb,
    const ushort_t* __restrict__ Wb1, const float* __restrict__ b1,
    ushort_t* __restrict__ h1b) {
    __shared__ short8 wl8[2048];                 // 32 KB
    ushort_t* wl = (ushort_t*)wl8;
#pragma unroll
    for (int it = 0; it < 8; it++) {
        int q = it * 256 + threadIdx.x;
        int n = q >> 4, c = q & 15;
        short8 v = ((const short8*)Wb1)[q];
        *(short8*)(wl + n * HID + ((c ^ (n & 7)) << 3)) = v;
    }
    __syncthreads();

    int wave = threadIdx.x >> 6;
    int lane = threadIdx.x & 63;
    int half = lane >> 5, col = lane & 31;

#pragma unroll
    for (int mt = 0; mt < 2; mt++) {
        int nb = blockIdx.x * 256 + mt * 128 + wave * 32;
        if (nb >= N_NODES) continue;             // no barriers below: safe
        int nA = nb + col;
        if (nA >= N_NODES) nA = N_NODES - 1;

        short8 areg[8];
#pragma unroll
        for (int s = 0; s < 4; s++)
            areg[s] = *(const short8*)(aggb + (size_t)nA * FIN + s * 16 + half * 8);
#pragma unroll
        for (int s = 4; s < 8; s++)
            areg[s] = *(const short8*)(xb + (size_t)nA * FIN + (s - 4) * 16 + half * 8);

        fx16 acc[4];
#pragma unroll
        for (int jt = 0; jt < 4; jt++)
#pragma unroll
            for (int r = 0; r < 16; r++) acc[jt][r] = 0.f;

#pragma unroll
        for (int s = 0; s < 8; s++) {
            int c = 2 * s + half;
#pragma unroll
            for (int jt = 0; jt < 4; jt++) {
                int n = jt * 32 + col;
                short8 bq = *(const short8*)(wl + n * HID + ((c ^ (n & 7)) << 3));
                acc[jt] = __builtin_amdgcn_mfma_f32_32x32x16_bf16(areg[s], bq, acc[jt], 0, 0, 0);
            }
        }
#pragma unroll
        for (int jt = 0; jt < 4; jt++) {
            int j = jt * 32 + col;
            float bias = b1[j];
#pragma unroll
            for (int r = 0; r < 16; r++) {
                int node = nb + (r & 3) + 8 * (r >> 2) + 4 * half;
                if (node < N_NODES) {
                    float v = acc[jt][r] + bias;
                    v = v > 0.f ? v : __expf(v) - 1.f;
                    h1b[(size_t)node * HID + j] = f2bf(v);
                }
            }
        }
    }
}

// ------- MFMA GEMM layer 2 + MFMA MLP head -------
__global__ __launch_bounds__(256) void g2h_kernel(
    const ushort_t* __restrict__ agg2b, const ushort_t* __restrict__ h1b,
    const ushort_t* __restrict__ Wb2, const float* __restrict__ b2,
    const float* __restrict__ Wfc1, const float* __restrict__ bfc1,
    const float* __restrict__ Wfc2, const float* __restrict__ bfc2,
    float* __restrict__ out) {
    __shared__ ushort_t smem[21504];             // 43008 B
    ushort_t* wl = smem;                         // 32 KB Wb2 K-half staging / t2 tile
    ushort_t* wf = smem + 17408;                 // 8 KB Wfc1 padded 32x128

#pragma unroll
    for (int it = 0; it < 16; it++) {
        int idx = it * 256 + threadIdx.x;        // 0..4095
        int m = idx >> 7, k = idx & 127;
        float v = (m < 20) ? Wfc1[m * HID + k] : 0.f;
        wf[m * 128 + (((k >> 3) ^ (m & 7)) << 3) + (k & 7)] = f2bf(v);
    }
#pragma unroll
    for (int it = 0; it < 8; it++) {
        int q = it * 256 + threadIdx.x;          // 0..2047
        int n = q >> 4, c = q & 15;
        short8 v = *(const short8*)(Wb2 + (size_t)n * 256 + c * 8);
        *(short8*)(wl + n * 128 + ((c ^ (n & 7)) << 3)) = v;
    }

    int wave = threadIdx.x >> 6;
    int lane = threadIdx.x & 63;
    int half = lane >> 5, col = lane & 31;
    int nb = blockIdx.x * 128 + wave * 32;       // tail waves keep running (barriers!)
    int nA = nb + col;
    if (nA >= N_NODES) nA = N_NODES - 1;

    short8 areg[16];
#pragma unroll
    for (int s = 0; s < 8; s++)
        areg[s] = *(const short8*)(agg2b + (size_t)nA * HID + s * 16 + half * 8);
#pragma unroll
    for (int s = 8; s < 16; s++)
        areg[s] = *(const short8*)(h1b + (size_t)nA * HID + (s - 8) * 16 + half * 8);

    fx16 acc[4];
#pragma unroll
    for (int jt = 0; jt < 4; jt++)
#pragma unroll
        for (int r = 0; r < 16; r++) acc[jt][r] = 0.f;

    __syncthreads();
#pragma unroll
    for (int s = 0; s < 8; s++) {                // K 0..127 (agg2 part)
        int c = 2 * s + half;
#pragma unroll
        for (int jt = 0; jt < 4; jt++) {
            int n = jt * 32 + col;
            short8 bq = *(const short8*)(wl + n * 128 + ((c ^ (n & 7)) << 3));
            acc[jt] = __builtin_amdgcn_mfma_f32_32x32x16_bf16(areg[s], bq, acc[jt], 0, 0, 0);
        }
    }
    __syncthreads();
#pragma unroll
    for (int it = 0; it < 8; it++) {             // stage K-half 1
        int q = it * 256 + threadIdx.x;
        int n = q >> 4, c = q & 15;
        short8 v = *(const short8*)(Wb2 + (size_t)n * 256 + 128 + c * 8);
        *(short8*)(wl + n * 128 + ((c ^ (n & 7)) << 3)) = v;
    }
    __syncthreads();
#pragma unroll
    for (int s = 8; s < 16; s++) {               // K 128..255 (h1 part)
        int c = 2 * (s - 8) + half;
#pragma unroll
        for (int jt = 0; jt < 4; jt++) {
            int n = jt * 32 + col;
            short8 bq = *(const short8*)(wl + n * 128 + ((c ^ (n & 7)) << 3));
            acc[jt] = __builtin_amdgcn_mfma_f32_32x32x16_bf16(areg[s], bq, acc[jt], 0, 0, 0);
        }
    }
    __syncthreads();   // weights dead; reuse as t2 tile

    ushort_t* tl = smem;                         // [node][feature], stride 136
#pragma unroll
    for (int jt = 0; jt < 4; jt++) {
        int j = jt * 32 + col;
        float bias = b2[j];
#pragma unroll
        for (int r = 0; r < 16; r++) {
            int nl = wave * 32 + (r & 3) + 8 * (r >> 2) + 4 * half;
            tl[nl * 136 + j] = f2bf(acc[jt][r] + bias);
        }
    }
    __syncthreads();

    short8 af[8];
#pragma unroll
    for (int s = 0; s < 8; s++)
        af[s] = *(const short8*)(tl + (wave * 32 + col) * 136 + s * 16 + half * 8);
    fx16 fa;
#pragma unroll
    for (int r = 0; r < 16; r++) fa[r] = 0.f;
#pragma unroll
    for (int s = 0; s < 8; s++) {
        int c = 2 * s + half;
        short8 bw = *(const short8*)(wf + col * 128 + ((c ^ (col & 7)) << 3));
        fa = __builtin_amdgcn_mfma_f32_32x32x16_bf16(af[s], bw, fa, 0, 0, 0);
    }
    float biasv = (col < 20) ? bfc1[col] : 0.f;
    float w2v = (col < 20) ? Wfc2[col] : 0.f;
    float bz = bfc2[0];
    float red[16];
#pragma unroll
    for (int r = 0; r < 16; r++) {
        float v = fa[r] + biasv;
        v = (v > 0.f ? v : 0.f) * w2v;
        v += __shfl_xor(v, 1);
        v += __shfl_xor(v, 2);
        v += __shfl_xor(v, 4);
        v += __shfl_xor(v, 8);
        v += __shfl_xor(v, 16);
        red[r] = v;
    }
    if (col == 0) {
#pragma unroll
        for (int r = 0; r < 16; r++) {
            int nl = wave * 32 + (r & 3) + 8 * (r >> 2) + 4 * half;
            int ng = blockIdx.x * 128 + nl;
            if (ng < N_NODES) out[ng] = red[r] + bz;
        }
    }
}

// ---------------- launch ----------------
extern "C" void kernel_launch(void* const* d_in, const int* in_sizes, int n_in,
                              void* d_out, int out_size, void* d_ws, size_t ws_size,
                              hipStream_t stream) {
    const float* x = (const float*)d_in[0];
    const int* ei = (const int*)d_in[1];
    const float* W1rel = (const float*)d_in[2];
    const float* b1 = (const float*)d_in[3];
    const float* W1root = (const float*)d_in[4];
    const float* W2rel = (const float*)d_in[5];
    const float* b2 = (const float*)d_in[6];
    const float* W2root = (const float*)d_in[7];
    const float* Wfc1 = (const float*)d_in[8];
    const float* bfc1 = (const float*)d_in[9];
    const float* Wfc2 = (const float*)d_in[10];
    const float* bfc2 = (const float*)d_in[11];
    float* out = (float*)d_out;

    char* ws = (char*)d_ws;
    size_t o = 0;
    int* deg = (int*)(ws + o);       o += (size_t)N_NODES * 4;
    int* off = (int*)(ws + o);       o += (size_t)(N_NODES + 1) * 4 + 12;
    int* bsums = (int*)(ws + o);     o += 4096;
    int* flag = (int*)(ws + o);      o += 16;
    int* rank = (int*)(ws + o);      o += (size_t)N_EDGES * 4;              // 3.2 MB
    int* srcs = (int*)(ws + o);      o += (size_t)N_EDGES * 4;              // 3.2 MB
    ushort_t* xb = (ushort_t*)(ws + o);    o += (size_t)(N_NODES + 1) * FIN * 2;  // +sentinel
    ushort_t* agg1b = (ushort_t*)(ws + o); o += (size_t)N_NODES * FIN * 2;
    ushort_t* h1b = (ushort_t*)(ws + o);   o += (size_t)(N_NODES + 1) * HID * 2;  // +sentinel
    ushort_t* agg2b = (ushort_t*)(ws + o); o += (size_t)N_NODES * HID * 2;
    ushort_t* Wb1 = (ushort_t*)(ws + o);   o += (size_t)HID * HID * 2;
    ushort_t* Wb2 = (ushort_t*)(ws + o);   o += (size_t)HID * 2 * HID * 2;

    const int GW2 = (N_NODES + 127) / 128; // 782 blocks (g2h)
    const int GW1 = (N_NODES + 255) / 256; // 391 blocks (g1, 2 M-tiles/wave)

    prep_kernel<<<(N_NODES * FIN / 4 + 255) / 256, 256, 0, stream>>>(
        x, xb, W1rel, W1root, W2rel, W2root, Wb1, Wb2, deg, flag, h1b);
    detect_kernel<<<32, 256, 0, stream>>>(ei, flag);
    hist_kernel<<<(N_EDGES + 255) / 256, 256, 0, stream>>>(ei, flag, deg, rank);
    scan1_kernel<<<NB1, 256, 0, stream>>>(deg, off, bsums);
    scan2_kernel<<<1, 512, 0, stream>>>(bsums);
    scan3_kernel<<<NB1, 256, 0, stream>>>(off, bsums);
    scatter_kernel<<<(N_EDGES + 255) / 256, 256, 0, stream>>>(ei, flag, off, rank, srcs);
    agg1_kernel<<<N_NODES / 4, 256, 0, stream>>>(xb, off, srcs, agg1b);
    g1_kernel<<<GW1, 256, 0, stream>>>(agg1b, xb, Wb1, b1, h1b);
    agg2_kernel<<<N_NODES / 4, 256, 0, stream>>>(h1b, off, srcs, agg2b);
    g2h_kernel<<<GW2, 256, 0, stream>>>(agg2b, h1b, Wb2, b2, Wfc1, bfc1, Wfc2, bfc2, out);
}